// Round 1
// 1311.353 us; speedup vs baseline: 1.0261x; 1.0261x over previous
//
#include <hip/hip_runtime.h>
#include <hip/hip_bf16.h>

typedef __hip_bfloat16 bf16;
typedef __attribute__((ext_vector_type(8))) short short8;
typedef __attribute__((ext_vector_type(4))) short short4v;
typedef __attribute__((ext_vector_type(4))) float f32x4;
typedef unsigned short u16;
#define BF2F(x) __bfloat162float(x)

__device__ __forceinline__ u16 f2bfbits(float v) {
  bf16 h = __float2bfloat16(v);
  return *(u16*)&h;
}
__device__ __forceinline__ float bfbits2f(u16 u) {
  bf16 h; *(u16*)&h = u;
  return BF2F(h);
}
__device__ __forceinline__ void splitbf(float v, u16& hi, u16& lo) {
  hi = f2bfbits(v);
  lo = f2bfbits(v - bfbits2f(hi));
}

union VecU {
  u16 u[8];
  short8 s;
};

// ---------------- NCHW(f32) -> NHWC(f32) ----------------
__global__ void nchw2nhwc_kernel(const float* __restrict__ in, float* __restrict__ out,
                                 int B, int C, int HW) {
  int i = blockIdx.x * blockDim.x + threadIdx.x;
  int total = B * C * HW;
  if (i >= total) return;
  int c = i % C; int p = (i / C) % HW; int b = i / (C * HW);
  out[i] = in[((size_t)b * C + c) * HW + p];
}

// ------- conv weight: w[co][ci][k2] -> bf16 hi/lo [co][k2*C+ci], zero-padded to Kp -------
__global__ void wtc_kernel(const float* __restrict__ w, u16* __restrict__ Wh,
                           u16* __restrict__ Wl, int N, int C, int Kp) {
  int i = blockIdx.x * blockDim.x + threadIdx.x;
  if (i >= N * Kp) return;
  int k = i % Kp; int co = i / Kp;
  int K = 9 * C;
  float v = 0.f;
  if (k < K) {
    int ci = k % C; int k2 = k / C;
    v = w[((size_t)co * C + ci) * 9 + k2];
  }
  u16 hh, ll; splitbf(v, hh, ll);
  Wh[i] = hh; Wl[i] = ll;
}

// ------- fp32 activations (+opt bias+relu) -> bf16 hi/lo pair -------
__global__ void act_convert(const float* __restrict__ x, const float* __restrict__ bias,
                            int relu, u16* __restrict__ Ah, u16* __restrict__ Al,
                            int total, int Cc) {
  int i = blockIdx.x * blockDim.x + threadIdx.x;
  if (i >= total) return;
  float v = x[i];
  if (bias) v += bias[i % Cc];
  if (relu && v < 0.f) v = 0.f;
  u16 hh, ll; splitbf(v, hh, ll);
  Ah[i] = hh; Al[i] = ll;
}

// ------- flattened deformable sampling: thread = (pixel, k2, c4-chunk) -------
// fused BN(scale/shift)+ReLU on gathered values; writes bf16 hi/lo pair
__global__ __launch_bounds__(256) void deform_sample_v2(
    const float* __restrict__ act, const float* __restrict__ stp, int bnmode,
    const float* __restrict__ off, u16* __restrict__ Sh, u16* __restrict__ Sl,
    int m0, int Mc, int B, int H, int W, int C, int Kp) {
  int i = blockIdx.x * blockDim.x + threadIdx.x;
  int c4n = C >> 2;
  int total = Mc * 9 * c4n;
  if (i >= total) return;
  int c4 = i % c4n;
  int t = i / c4n;
  int k2 = t % 9;
  int ml = t / 9;
  int m = m0 + ml;
  int HW = H * W;
  int b = m / HW; int p = m - b * HW; int y = p / W; int x = p - y * W;
  size_t ob = (size_t)b * 18 * HW + p;
  float dy = off[ob + (size_t)(2 * k2) * HW];
  float dx = off[ob + (size_t)(2 * k2 + 1) * HW];
  float py = (float)(y + k2 / 3 - 1) + dy;
  float px = (float)(x + k2 % 3 - 1) + dx;
  float y0f = floorf(py), x0f = floorf(px);
  float wy = py - y0f, wx = px - x0f;
  int iy0 = (int)y0f, ix0 = (int)x0f;
  int iy1 = iy0 + 1, ix1 = ix0 + 1;
  float w00 = (1.f - wy) * (1.f - wx), w01 = (1.f - wy) * wx;
  float w10 = wy * (1.f - wx), w11 = wy * wx;
  if (iy0 < 0 || iy0 >= H) { w00 = 0.f; w01 = 0.f; }
  if (iy1 < 0 || iy1 >= H) { w10 = 0.f; w11 = 0.f; }
  if (ix0 < 0 || ix0 >= W) { w00 = 0.f; w10 = 0.f; }
  if (ix1 < 0 || ix1 >= W) { w01 = 0.f; w11 = 0.f; }
  int cy0 = min(max(iy0, 0), H - 1), cy1 = min(max(iy1, 0), H - 1);
  int cx0 = min(max(ix0, 0), W - 1), cx1 = min(max(ix1, 0), W - 1);
  int c = c4 << 2;
  size_t rowb = (size_t)b * HW;
  float4 v00 = *(const float4*)(act + (rowb + cy0 * W + cx0) * C + c);
  float4 v01 = *(const float4*)(act + (rowb + cy0 * W + cx1) * C + c);
  float4 v10 = *(const float4*)(act + (rowb + cy1 * W + cx0) * C + c);
  float4 v11 = *(const float4*)(act + (rowb + cy1 * W + cx1) * C + c);
  if (bnmode) {
    float4 sc = *(const float4*)(stp + c);
    float4 sh = *(const float4*)(stp + 512 + c);
    v00.x = fmaxf(v00.x * sc.x + sh.x, 0.f); v00.y = fmaxf(v00.y * sc.y + sh.y, 0.f);
    v00.z = fmaxf(v00.z * sc.z + sh.z, 0.f); v00.w = fmaxf(v00.w * sc.w + sh.w, 0.f);
    v01.x = fmaxf(v01.x * sc.x + sh.x, 0.f); v01.y = fmaxf(v01.y * sc.y + sh.y, 0.f);
    v01.z = fmaxf(v01.z * sc.z + sh.z, 0.f); v01.w = fmaxf(v01.w * sc.w + sh.w, 0.f);
    v10.x = fmaxf(v10.x * sc.x + sh.x, 0.f); v10.y = fmaxf(v10.y * sc.y + sh.y, 0.f);
    v10.z = fmaxf(v10.z * sc.z + sh.z, 0.f); v10.w = fmaxf(v10.w * sc.w + sh.w, 0.f);
    v11.x = fmaxf(v11.x * sc.x + sh.x, 0.f); v11.y = fmaxf(v11.y * sc.y + sh.y, 0.f);
    v11.z = fmaxf(v11.z * sc.z + sh.z, 0.f); v11.w = fmaxf(v11.w * sc.w + sh.w, 0.f);
  }
  float4 r;
  r.x = w00 * v00.x + w01 * v01.x + w10 * v10.x + w11 * v11.x;
  r.y = w00 * v00.y + w01 * v01.y + w10 * v10.y + w11 * v11.y;
  r.z = w00 * v00.z + w01 * v01.z + w10 * v10.z + w11 * v11.z;
  r.w = w00 * v00.w + w01 * v01.w + w10 * v10.w + w11 * v11.w;
  short4v h, lo;
  u16 hh, ll;
  splitbf(r.x, hh, ll); h.x = (short)hh; lo.x = (short)ll;
  splitbf(r.y, hh, ll); h.y = (short)hh; lo.y = (short)ll;
  splitbf(r.z, hh, ll); h.z = (short)hh; lo.z = (short)ll;
  splitbf(r.w, hh, ll); h.w = (short)hh; lo.w = (short)ll;
  size_t base = (size_t)ml * Kp + (size_t)k2 * C + c;
  *(short4v*)(Sh + base) = h;
  *(short4v*)(Sl + base) = lo;
}

// ------- scalar variant for layer 1 (C=3, K=27, Kp=32; covers zero padding) -------
__global__ __launch_bounds__(256) void deform_sample_scalar(
    const float* __restrict__ act, const float* __restrict__ off,
    u16* __restrict__ Sh, u16* __restrict__ Sl,
    int m0, int Mc, int B, int H, int W, int C, int Kp) {
  int i = blockIdx.x * blockDim.x + threadIdx.x;
  int total = Mc * Kp;
  if (i >= total) return;
  int kp = i % Kp;
  int ml = i / Kp;
  float val = 0.f;
  int K = 9 * C;
  if (kp < K) {
    int c = kp % C; int k2 = kp / C;
    int m = m0 + ml;
    int HW = H * W;
    int b = m / HW; int p = m - b * HW; int y = p / W; int x = p - y * W;
    size_t ob = (size_t)b * 18 * HW + p;
    float dy = off[ob + (size_t)(2 * k2) * HW];
    float dx = off[ob + (size_t)(2 * k2 + 1) * HW];
    float py = (float)(y + k2 / 3 - 1) + dy;
    float px = (float)(x + k2 % 3 - 1) + dx;
    float y0f = floorf(py), x0f = floorf(px);
    float wy = py - y0f, wx = px - x0f;
    int iy0 = (int)y0f, ix0 = (int)x0f;
    int iy1 = iy0 + 1, ix1 = ix0 + 1;
    float w00 = (1.f - wy) * (1.f - wx), w01 = (1.f - wy) * wx;
    float w10 = wy * (1.f - wx), w11 = wy * wx;
    if (iy0 < 0 || iy0 >= H) { w00 = 0.f; w01 = 0.f; }
    if (iy1 < 0 || iy1 >= H) { w10 = 0.f; w11 = 0.f; }
    if (ix0 < 0 || ix0 >= W) { w00 = 0.f; w10 = 0.f; }
    if (ix1 < 0 || ix1 >= W) { w01 = 0.f; w11 = 0.f; }
    int cy0 = min(max(iy0, 0), H - 1), cy1 = min(max(iy1, 0), H - 1);
    int cx0 = min(max(ix0, 0), W - 1), cx1 = min(max(ix1, 0), W - 1);
    size_t rowb = (size_t)b * HW;
    float v00 = act[(rowb + cy0 * W + cx0) * C + c];
    float v01 = act[(rowb + cy0 * W + cx1) * C + c];
    float v10 = act[(rowb + cy1 * W + cx0) * C + c];
    float v11 = act[(rowb + cy1 * W + cx1) * C + c];
    val = w00 * v00 + w01 * v01 + w10 * v10 + w11 * v11;
  }
  u16 hh, ll; splitbf(val, hh, ll);
  size_t base = (size_t)ml * Kp + kp;
  Sh[base] = hh; Sl[base] = ll;
}

// ---------------- barrier-free direct-fragment MFMA GEMM (bf16x3) ----------------
// 1 wave per block, 32x32 output tile, fragments loaded straight from global.
// A: bf16 hi/lo [M][Kp], B: bf16 hi/lo [N][Kp]. M,N multiples of 32, Kp multiple of 32.
__global__ __launch_bounds__(64) void mfma_gemm_frag(
    const u16* __restrict__ Ah, const u16* __restrict__ Al,
    const u16* __restrict__ Bh, const u16* __restrict__ Bl,
    float* __restrict__ Cf, int M, int N, int Kp, int kPerZ, int atomicMode) {
  int lane = threadIdx.x;
  int l15 = lane & 15, quad = lane >> 4;
  int m0 = blockIdx.x * 32, n0 = blockIdx.y * 32;
  int kStart = blockIdx.z * kPerZ;
  int kEnd = min(Kp, kStart + kPerZ);
  f32x4 z4 = {0.f, 0.f, 0.f, 0.f};
  f32x4 acc00 = z4, acc01 = z4, acc10 = z4, acc11 = z4;
  const u16* pa0 = Ah + (size_t)(m0 + l15) * Kp + (quad << 3);
  const u16* pa1 = pa0 + (size_t)16 * Kp;
  const u16* qa0 = Al + (size_t)(m0 + l15) * Kp + (quad << 3);
  const u16* qa1 = qa0 + (size_t)16 * Kp;
  const u16* pb0 = Bh + (size_t)(n0 + l15) * Kp + (quad << 3);
  const u16* pb1 = pb0 + (size_t)16 * Kp;
  const u16* qb0 = Bl + (size_t)(n0 + l15) * Kp + (quad << 3);
  const u16* qb1 = qb0 + (size_t)16 * Kp;
#pragma unroll 2
  for (int k0 = kStart; k0 < kEnd; k0 += 32) {
    short8 ah0 = *(const short8*)(pa0 + k0);
    short8 ah1 = *(const short8*)(pa1 + k0);
    short8 al0 = *(const short8*)(qa0 + k0);
    short8 al1 = *(const short8*)(qa1 + k0);
    short8 bh0 = *(const short8*)(pb0 + k0);
    short8 bh1 = *(const short8*)(pb1 + k0);
    short8 bl0 = *(const short8*)(qb0 + k0);
    short8 bl1 = *(const short8*)(qb1 + k0);
    acc00 = __builtin_amdgcn_mfma_f32_16x16x32_bf16(ah0, bh0, acc00, 0, 0, 0);
    acc01 = __builtin_amdgcn_mfma_f32_16x16x32_bf16(ah0, bh1, acc01, 0, 0, 0);
    acc10 = __builtin_amdgcn_mfma_f32_16x16x32_bf16(ah1, bh0, acc10, 0, 0, 0);
    acc11 = __builtin_amdgcn_mfma_f32_16x16x32_bf16(ah1, bh1, acc11, 0, 0, 0);
    acc00 = __builtin_amdgcn_mfma_f32_16x16x32_bf16(ah0, bl0, acc00, 0, 0, 0);
    acc01 = __builtin_amdgcn_mfma_f32_16x16x32_bf16(ah0, bl1, acc01, 0, 0, 0);
    acc10 = __builtin_amdgcn_mfma_f32_16x16x32_bf16(ah1, bl0, acc10, 0, 0, 0);
    acc11 = __builtin_amdgcn_mfma_f32_16x16x32_bf16(ah1, bl1, acc11, 0, 0, 0);
    acc00 = __builtin_amdgcn_mfma_f32_16x16x32_bf16(al0, bh0, acc00, 0, 0, 0);
    acc01 = __builtin_amdgcn_mfma_f32_16x16x32_bf16(al0, bh1, acc01, 0, 0, 0);
    acc10 = __builtin_amdgcn_mfma_f32_16x16x32_bf16(al1, bh0, acc10, 0, 0, 0);
    acc11 = __builtin_amdgcn_mfma_f32_16x16x32_bf16(al1, bh1, acc11, 0, 0, 0);
  }
  f32x4 av[2][2] = {{acc00, acc01}, {acc10, acc11}};
#pragma unroll
  for (int t = 0; t < 2; ++t) {
    int mB = m0 + t * 16 + (quad << 2);
#pragma unroll
    for (int u = 0; u < 2; ++u) {
      int n = n0 + u * 16 + l15;
      if (n >= N) continue;
      f32x4 a = av[t][u];
#pragma unroll
      for (int reg = 0; reg < 4; ++reg) {
        int m = mB + reg;
        if (m >= M) continue;
        if (atomicMode) atomicAdd(&Cf[(size_t)m * N + n], a[reg]);
        else Cf[(size_t)m * N + n] = a[reg];
      }
    }
  }
}

// ---------------- FC variant: A bf16 pair, B fp32 row-major (split in-kernel) ----------------
// Always split-K/atomic (output pre-zeroed). Guards B rows >= N (FC3 N=100).
__global__ __launch_bounds__(64) void mfma_gemm_fc(
    const u16* __restrict__ Ah, const u16* __restrict__ Al,
    const float* __restrict__ Bw, float* __restrict__ Cf,
    int M, int N, int K, int kPerZ) {
  int lane = threadIdx.x;
  int l15 = lane & 15, quad = lane >> 4;
  int m0 = blockIdx.x * 32, n0 = blockIdx.y * 32;
  int kStart = blockIdx.z * kPerZ;
  int kEnd = min(K, kStart + kPerZ);
  f32x4 z4 = {0.f, 0.f, 0.f, 0.f};
  f32x4 acc00 = z4, acc01 = z4, acc10 = z4, acc11 = z4;
  int nr0 = n0 + l15, nr1 = n0 + 16 + l15;
  bool v0 = nr0 < N, v1 = nr1 < N;
  const float* pb0 = Bw + (size_t)(v0 ? nr0 : 0) * K + (quad << 3);
  const float* pb1 = Bw + (size_t)(v1 ? nr1 : 0) * K + (quad << 3);
  const u16* pa0 = Ah + (size_t)(m0 + l15) * K + (quad << 3);
  const u16* pa1 = pa0 + (size_t)16 * K;
  const u16* qa0 = Al + (size_t)(m0 + l15) * K + (quad << 3);
  const u16* qa1 = qa0 + (size_t)16 * K;
  for (int k0 = kStart; k0 < kEnd; k0 += 32) {
    short8 ah0 = *(const short8*)(pa0 + k0);
    short8 ah1 = *(const short8*)(pa1 + k0);
    short8 al0 = *(const short8*)(qa0 + k0);
    short8 al1 = *(const short8*)(qa1 + k0);
    float4 x0 = *(const float4*)(pb0 + k0);
    float4 x1 = *(const float4*)(pb0 + k0 + 4);
    float4 y0 = *(const float4*)(pb1 + k0);
    float4 y1 = *(const float4*)(pb1 + k0 + 4);
    float f0[8] = {x0.x, x0.y, x0.z, x0.w, x1.x, x1.y, x1.z, x1.w};
    float f1[8] = {y0.x, y0.y, y0.z, y0.w, y1.x, y1.y, y1.z, y1.w};
    if (!v0) {
#pragma unroll
      for (int j = 0; j < 8; ++j) f0[j] = 0.f;
    }
    if (!v1) {
#pragma unroll
      for (int j = 0; j < 8; ++j) f1[j] = 0.f;
    }
    VecU bh0u, bl0u, bh1u, bl1u;
#pragma unroll
    for (int j = 0; j < 8; ++j) {
      splitbf(f0[j], bh0u.u[j], bl0u.u[j]);
      splitbf(f1[j], bh1u.u[j], bl1u.u[j]);
    }
    acc00 = __builtin_amdgcn_mfma_f32_16x16x32_bf16(ah0, bh0u.s, acc00, 0, 0, 0);
    acc01 = __builtin_amdgcn_mfma_f32_16x16x32_bf16(ah0, bh1u.s, acc01, 0, 0, 0);
    acc10 = __builtin_amdgcn_mfma_f32_16x16x32_bf16(ah1, bh0u.s, acc10, 0, 0, 0);
    acc11 = __builtin_amdgcn_mfma_f32_16x16x32_bf16(ah1, bh1u.s, acc11, 0, 0, 0);
    acc00 = __builtin_amdgcn_mfma_f32_16x16x32_bf16(ah0, bl0u.s, acc00, 0, 0, 0);
    acc01 = __builtin_amdgcn_mfma_f32_16x16x32_bf16(ah0, bl1u.s, acc01, 0, 0, 0);
    acc10 = __builtin_amdgcn_mfma_f32_16x16x32_bf16(ah1, bl0u.s, acc10, 0, 0, 0);
    acc11 = __builtin_amdgcn_mfma_f32_16x16x32_bf16(ah1, bl1u.s, acc11, 0, 0, 0);
    acc00 = __builtin_amdgcn_mfma_f32_16x16x32_bf16(al0, bh0u.s, acc00, 0, 0, 0);
    acc01 = __builtin_amdgcn_mfma_f32_16x16x32_bf16(al0, bh1u.s, acc01, 0, 0, 0);
    acc10 = __builtin_amdgcn_mfma_f32_16x16x32_bf16(al1, bh0u.s, acc10, 0, 0, 0);
    acc11 = __builtin_amdgcn_mfma_f32_16x16x32_bf16(al1, bh1u.s, acc11, 0, 0, 0);
  }
  f32x4 av[2][2] = {{acc00, acc01}, {acc10, acc11}};
#pragma unroll
  for (int t = 0; t < 2; ++t) {
    int mB = m0 + t * 16 + (quad << 2);
#pragma unroll
    for (int u = 0; u < 2; ++u) {
      int n = n0 + u * 16 + l15;
      if (n >= N) continue;
      f32x4 a = av[t][u];
#pragma unroll
      for (int reg = 0; reg < 4; ++reg) {
        int m = mB + reg;
        if (m >= M) continue;
        atomicAdd(&Cf[(size_t)m * N + n], a[reg]);
      }
    }
  }
}

// ---------------- bias (+optional relu) pass ----------------
__global__ void bias_act_kernel(float* __restrict__ x, const float* __restrict__ bias,
                                int total, int C, int relu) {
  int i = blockIdx.x * blockDim.x + threadIdx.x;
  if (i >= total) return;
  float v = x[i] + bias[i % C];
  if (relu && v < 0.f) v = 0.f;
  x[i] = v;
}

// ---------------- BN batch stats ----------------
__global__ __launch_bounds__(256) void bn_stats_kernel(const float* __restrict__ x,
                                                       float* __restrict__ st,
                                                       int M, int C, int rowsPerBlock) {
  __shared__ float sh[512];
  int t = threadIdx.x;
  int r0 = blockIdx.x * rowsPerBlock;
  int r1 = min(M, r0 + rowsPerBlock);
  if (C >= 256) {
    for (int c = t; c < C; c += 256) {
      float s = 0.f, ss = 0.f;
      for (int r = r0; r < r1; ++r) {
        float v = x[(size_t)r * C + c];
        s += v; ss += v * v;
      }
      atomicAdd(&st[c], s); atomicAdd(&st[512 + c], ss);
    }
  } else {
    int rpb = 256 / C;
    int c = t % C; int ro = t / C;
    float s = 0.f, ss = 0.f;
    for (int r = r0 + ro; r < r1; r += rpb) {
      float v = x[(size_t)r * C + c];
      s += v; ss += v * v;
    }
    sh[t] = s; sh[256 + t] = ss;
    __syncthreads();
    if (ro == 0) {
      for (int k = 1; k < rpb; ++k) { s += sh[k * C + c]; ss += sh[256 + k * C + c]; }
      atomicAdd(&st[c], s); atomicAdd(&st[512 + c], ss);
    }
  }
}

__global__ void bn_finalize_kernel(float* __restrict__ st, const float* __restrict__ g,
                                   const float* __restrict__ bb, int M, int C) {
  int c = threadIdx.x;
  if (c >= C) return;
  float mean = st[c] / (float)M;
  float var = st[512 + c] / (float)M - mean * mean;
  if (var < 0.f) var = 0.f;
  float inv = 1.0f / sqrtf(var + 1e-5f);
  float sc = g[c] * inv;
  st[1024 + c] = sc;
  st[1536 + c] = bb[c] - mean * sc;
}

// -------- permuted 2x2 max pool with fused BN+ReLU on inputs --------
__global__ void pool_kernel(const float* __restrict__ in, const float* __restrict__ stp,
                            float* __restrict__ out,
                            const int* __restrict__ perm, const int* __restrict__ nperm,
                            int B, int H, int C, int total) {
  int i = blockIdx.x * blockDim.x + threadIdx.x;
  if (i >= total) return;
  int oH = H / 2; int oHW = oH * oH; int HW = H * H;
  int c = i % C; int j = (i / C) % oHW; int b = i / (C * oHW);
  float sc = stp[c], sh = stp[512 + c];
  int q = min(max(nperm[j], 0), oHW - 1);
  int qy = q / oH, qx = q % oH;
  float m = 0.f;  // post-ReLU values are >= 0
#pragma unroll
  for (int dy = 0; dy < 2; ++dy)
#pragma unroll
    for (int dx = 0; dx < 2; ++dx) {
      int p = min(max(perm[(2 * qy + dy) * H + (2 * qx + dx)], 0), HW - 1);
      float v = in[((size_t)b * HW + p) * C + c];
      v = fmaxf(v * sc + sh, 0.f);
      m = fmaxf(m, v);
    }
  out[((size_t)b * oHW + j) * C + c] = m;
}

// target >= 1536 one-wave blocks for latency hiding; kPerZ multiple of 32
static inline void pick_split(int gx, int gy, int Kp, int& zs, int& kPerZ) {
  int gxy = gx * gy;
  zs = 1;
  if (gxy < 1536) {
    zs = (1536 + gxy - 1) / gxy;
    int maxz = Kp / 32; if (maxz < 1) maxz = 1;
    if (zs > maxz) zs = maxz;
  }
  kPerZ = (((Kp + zs - 1) / zs) + 31) & ~31;
  zs = (Kp + kPerZ - 1) / kPerZ;
}

extern "C" void kernel_launch(void* const* d_in, const int* in_sizes, int n_in,
                              void* d_out, int out_size, void* d_ws, size_t ws_size,
                              hipStream_t stream) {
  const int Ci[13]  = {3, 64, 64, 128, 128, 256, 256, 256, 512, 512, 512, 512, 512};
  const int CoA[13] = {64, 64, 128, 128, 256, 256, 256, 512, 512, 512, 512, 512, 512};
  const int Rr[13]  = {32, 32, 16, 16, 8, 8, 8, 4, 4, 4, 2, 2, 2};
  const int poolAfter[13] = {-1, 0, -1, 1, -1, -1, 2, -1, -1, 3, -1, -1, 4};
  const int B = 32;

  size_t cursor = 0;
  auto alloc = [&](size_t bytes) {
    void* p = (char*)d_ws + cursor;
    cursor += (bytes + 255) & ~(size_t)255;
    return p;
  };
  float* stats = (float*)alloc((size_t)13 * 2048 * 4);
  float* fcA   = (float*)alloc((size_t)32 * 4096 * 4);
  u16*   fcPh  = (u16*)alloc((size_t)32 * 4096 * 2);
  u16*   fcPl  = (u16*)alloc((size_t)32 * 4096 * 2);
  float* A0    = (float*)alloc((size_t)2097152 * 4);   // 32768*64 fp32
  float* A1    = (float*)alloc((size_t)2097152 * 4);
  u16*   WTh   = (u16*)alloc((size_t)2359296 * 2);     // 512*4608 bf16 hi
  u16*   WTl   = (u16*)alloc((size_t)2359296 * 2);     // 512*4608 bf16 lo
  size_t remainBytes = (ws_size > cursor) ? (ws_size - cursor) : 0;
  size_t sElems = remainBytes / 4;                     // split across Sh+Sl (2B each)
  if (sElems > (size_t)8388608) sElems = 8388608;      // cap: 16MB per array
  if (sElems < (size_t)589824)  sElems = 589824;       // floor: 128 rows x K=4608
  u16* Sh = (u16*)alloc(sElems * 2);
  u16* Sl = (u16*)alloc(sElems * 2);
  (void)in_sizes; (void)n_in; (void)out_size;

  hipMemsetAsync(stats, 0, (size_t)13 * 2048 * 4, stream);

  {
    int total = B * 3 * 1024;
    nchw2nhwc_kernel<<<(total + 255) / 256, 256, 0, stream>>>(
        (const float*)d_in[0], A0, B, 3, 1024);
  }

  float* cur = A0;
  float* oth = A1;
  int needBN = 0;
  float* stp = nullptr;

  for (int l = 0; l < 13; ++l) {
    int C = Ci[l], N = CoA[l], H = Rr[l];
    int M = B * H * H, K = 9 * C, Kp = (K + 31) & ~31;
    const float* offp = (const float*)d_in[1 + l * 5 + 0];
    const float* wp   = (const float*)d_in[1 + l * 5 + 1];
    const float* gp   = (const float*)d_in[1 + l * 5 + 3];
    const float* bbp  = (const float*)d_in[1 + l * 5 + 4];
    float* st = stats + (size_t)l * 2048;

    wtc_kernel<<<(N * Kp + 255) / 256, 256, 0, stream>>>(wp, WTh, WTl, N, C, Kp);

    int MC = (int)((sElems / (size_t)Kp) & ~(size_t)63);
    if (MC < 64) MC = 64;
    if (MC > M) MC = M;
    for (int r0 = 0; r0 < M; r0 += MC) {
      int Mc = min(MC, M - r0);   // M, MC multiples of 64 -> Mc multiple of 64
      if ((C & 3) == 0) {
        int work = Mc * 9 * (C >> 2);
        deform_sample_v2<<<(work + 255) / 256, 256, 0, stream>>>(
            cur, stp, needBN, offp, Sh, Sl, r0, Mc, B, H, H, C, Kp);
      } else {
        int work = Mc * Kp;
        deform_sample_scalar<<<(work + 255) / 256, 256, 0, stream>>>(
            cur, offp, Sh, Sl, r0, Mc, B, H, H, C, Kp);
      }
      int gx = Mc / 32, gy = N / 32;
      int zs, kPerZ;
      pick_split(gx, gy, Kp, zs, kPerZ);
      if (zs > 1)
        hipMemsetAsync(oth + (size_t)r0 * N, 0, (size_t)Mc * N * 4, stream);
      mfma_gemm_frag<<<dim3(gx, gy, zs), 64, 0, stream>>>(
          Sh, Sl, WTh, WTl, oth + (size_t)r0 * N, Mc, N, Kp, kPerZ, zs > 1 ? 1 : 0);
    }

    int rowsPer = 64;
    bn_stats_kernel<<<(M + rowsPer - 1) / rowsPer, 256, 0, stream>>>(oth, st, M, N, rowsPer);
    bn_finalize_kernel<<<1, 512, 0, stream>>>(st, gp, bbp, M, N);

    if (poolAfter[l] >= 0) {
      int pi = poolAfter[l];
      const int* perm  = (const int*)d_in[66 + pi * 2];
      const int* nperm = (const int*)d_in[66 + pi * 2 + 1];
      int oH = H / 2;
      int total = B * oH * oH * N;
      pool_kernel<<<(total + 255) / 256, 256, 0, stream>>>(oth, st + 1024, cur,
                                                           perm, nperm, B, H, N, total);
      needBN = 0; stp = nullptr;
    } else {
      float* t = cur; cur = oth; oth = t;
      needBN = 1; stp = st + 1024;
    }
  }

  // FC head: cur = [32, 512] fp32 (BN+ReLU applied by final pool)
  const float* fw1 = (const float*)d_in[76]; const float* fb1 = (const float*)d_in[77];
  const float* fw2 = (const float*)d_in[78]; const float* fb2 = (const float*)d_in[79];
  const float* fw3 = (const float*)d_in[80]; const float* fb3 = (const float*)d_in[81];
  {
    int zs, kPerZ;
    // conv output -> bf16 pair
    act_convert<<<(32 * 512 + 255) / 256, 256, 0, stream>>>(
        cur, nullptr, 0, fcPh, fcPl, 32 * 512, 512);
    // FC1: 32x4096x512
    hipMemsetAsync(fcA, 0, (size_t)32 * 4096 * 4, stream);
    pick_split(1, 128, 512, zs, kPerZ);
    mfma_gemm_fc<<<dim3(1, 128, zs), 64, 0, stream>>>(fcPh, fcPl, fw1, fcA,
                                                      32, 4096, 512, kPerZ);
    act_convert<<<(32 * 4096 + 255) / 256, 256, 0, stream>>>(
        fcA, fb1, 1, fcPh, fcPl, 32 * 4096, 4096);
    // FC2: 32x4096x4096
    hipMemsetAsync(fcA, 0, (size_t)32 * 4096 * 4, stream);
    pick_split(1, 128, 4096, zs, kPerZ);
    mfma_gemm_fc<<<dim3(1, 128, zs), 64, 0, stream>>>(fcPh, fcPl, fw2, fcA,
                                                      32, 4096, 4096, kPerZ);
    act_convert<<<(32 * 4096 + 255) / 256, 256, 0, stream>>>(
        fcA, fb2, 1, fcPh, fcPl, 32 * 4096, 4096);
    // FC3: 32x100x4096
    hipMemsetAsync(d_out, 0, (size_t)3200 * 4, stream);
    pick_split(1, 4, 4096, zs, kPerZ);
    mfma_gemm_fc<<<dim3(1, 4, zs), 64, 0, stream>>>(fcPh, fcPl, fw3, (float*)d_out,
                                                    32, 100, 4096, kPerZ);
    bias_act_kernel<<<(3200 + 255) / 256, 256, 0, stream>>>((float*)d_out, fb3, 3200, 100, 0);
  }
}

// Round 2
// 1159.935 us; speedup vs baseline: 1.1601x; 1.1305x over previous
//
#include <hip/hip_runtime.h>
#include <hip/hip_bf16.h>

typedef __hip_bfloat16 bf16;
typedef __attribute__((ext_vector_type(8))) short short8;
typedef __attribute__((ext_vector_type(4))) short short4v;
typedef __attribute__((ext_vector_type(4))) float f32x4;
typedef unsigned short u16;
#define BF2F(x) __bfloat162float(x)

__device__ __forceinline__ u16 f2bfbits(float v) {
  bf16 h = __float2bfloat16(v);
  return *(u16*)&h;
}
__device__ __forceinline__ float bfbits2f(u16 u) {
  bf16 h; *(u16*)&h = u;
  return BF2F(h);
}
__device__ __forceinline__ void splitbf(float v, u16& hi, u16& lo) {
  hi = f2bfbits(v);
  lo = f2bfbits(v - bfbits2f(hi));
}

union VecU {
  u16 u[8];
  short8 s;
};

// ---------------- NCHW(f32) -> NHWC(f32) ----------------
__global__ void nchw2nhwc_kernel(const float* __restrict__ in, float* __restrict__ out,
                                 int B, int C, int HW) {
  int i = blockIdx.x * blockDim.x + threadIdx.x;
  int total = B * C * HW;
  if (i >= total) return;
  int c = i % C; int p = (i / C) % HW; int b = i / (C * HW);
  out[i] = in[((size_t)b * C + c) * HW + p];
}

// ------- conv weight: w[co][ci][k2] -> bf16 hi/lo [co][k2*C+ci], zero-padded to Kp -------
__global__ void wtc_kernel(const float* __restrict__ w, u16* __restrict__ Wh,
                           u16* __restrict__ Wl, int N, int C, int Kp) {
  int i = blockIdx.x * blockDim.x + threadIdx.x;
  if (i >= N * Kp) return;
  int k = i % Kp; int co = i / Kp;
  int K = 9 * C;
  float v = 0.f;
  if (k < K) {
    int ci = k % C; int k2 = k / C;
    v = w[((size_t)co * C + ci) * 9 + k2];
  }
  u16 hh, ll; splitbf(v, hh, ll);
  Wh[i] = hh; Wl[i] = ll;
}

// ------- fp32 activations (+opt bias+relu) -> bf16 hi/lo pair -------
__global__ void act_convert(const float* __restrict__ x, const float* __restrict__ bias,
                            int relu, u16* __restrict__ Ah, u16* __restrict__ Al,
                            int total, int Cc) {
  int i = blockIdx.x * blockDim.x + threadIdx.x;
  if (i >= total) return;
  float v = x[i];
  if (bias) v += bias[i % Cc];
  if (relu && v < 0.f) v = 0.f;
  u16 hh, ll; splitbf(v, hh, ll);
  Ah[i] = hh; Al[i] = ll;
}

// ------- flattened deformable sampling: thread = (pixel, k2, c4-chunk) -------
// fused BN(scale/shift)+ReLU on gathered values; writes bf16 hi/lo pair
__global__ __launch_bounds__(256) void deform_sample_v2(
    const float* __restrict__ act, const float* __restrict__ stp, int bnmode,
    const float* __restrict__ off, u16* __restrict__ Sh, u16* __restrict__ Sl,
    int m0, int Mc, int B, int H, int W, int C, int Kp) {
  int i = blockIdx.x * blockDim.x + threadIdx.x;
  int c4n = C >> 2;
  int total = Mc * 9 * c4n;
  if (i >= total) return;
  int c4 = i % c4n;
  int t = i / c4n;
  int k2 = t % 9;
  int ml = t / 9;
  int m = m0 + ml;
  int HW = H * W;
  int b = m / HW; int p = m - b * HW; int y = p / W; int x = p - y * W;
  size_t ob = (size_t)b * 18 * HW + p;
  float dy = off[ob + (size_t)(2 * k2) * HW];
  float dx = off[ob + (size_t)(2 * k2 + 1) * HW];
  float py = (float)(y + k2 / 3 - 1) + dy;
  float px = (float)(x + k2 % 3 - 1) + dx;
  float y0f = floorf(py), x0f = floorf(px);
  float wy = py - y0f, wx = px - x0f;
  int iy0 = (int)y0f, ix0 = (int)x0f;
  int iy1 = iy0 + 1, ix1 = ix0 + 1;
  float w00 = (1.f - wy) * (1.f - wx), w01 = (1.f - wy) * wx;
  float w10 = wy * (1.f - wx), w11 = wy * wx;
  if (iy0 < 0 || iy0 >= H) { w00 = 0.f; w01 = 0.f; }
  if (iy1 < 0 || iy1 >= H) { w10 = 0.f; w11 = 0.f; }
  if (ix0 < 0 || ix0 >= W) { w00 = 0.f; w10 = 0.f; }
  if (ix1 < 0 || ix1 >= W) { w01 = 0.f; w11 = 0.f; }
  int cy0 = min(max(iy0, 0), H - 1), cy1 = min(max(iy1, 0), H - 1);
  int cx0 = min(max(ix0, 0), W - 1), cx1 = min(max(ix1, 0), W - 1);
  int c = c4 << 2;
  size_t rowb = (size_t)b * HW;
  float4 v00 = *(const float4*)(act + (rowb + cy0 * W + cx0) * C + c);
  float4 v01 = *(const float4*)(act + (rowb + cy0 * W + cx1) * C + c);
  float4 v10 = *(const float4*)(act + (rowb + cy1 * W + cx0) * C + c);
  float4 v11 = *(const float4*)(act + (rowb + cy1 * W + cx1) * C + c);
  if (bnmode) {
    float4 sc = *(const float4*)(stp + c);
    float4 sh = *(const float4*)(stp + 512 + c);
    v00.x = fmaxf(v00.x * sc.x + sh.x, 0.f); v00.y = fmaxf(v00.y * sc.y + sh.y, 0.f);
    v00.z = fmaxf(v00.z * sc.z + sh.z, 0.f); v00.w = fmaxf(v00.w * sc.w + sh.w, 0.f);
    v01.x = fmaxf(v01.x * sc.x + sh.x, 0.f); v01.y = fmaxf(v01.y * sc.y + sh.y, 0.f);
    v01.z = fmaxf(v01.z * sc.z + sh.z, 0.f); v01.w = fmaxf(v01.w * sc.w + sh.w, 0.f);
    v10.x = fmaxf(v10.x * sc.x + sh.x, 0.f); v10.y = fmaxf(v10.y * sc.y + sh.y, 0.f);
    v10.z = fmaxf(v10.z * sc.z + sh.z, 0.f); v10.w = fmaxf(v10.w * sc.w + sh.w, 0.f);
    v11.x = fmaxf(v11.x * sc.x + sh.x, 0.f); v11.y = fmaxf(v11.y * sc.y + sh.y, 0.f);
    v11.z = fmaxf(v11.z * sc.z + sh.z, 0.f); v11.w = fmaxf(v11.w * sc.w + sh.w, 0.f);
  }
  float4 r;
  r.x = w00 * v00.x + w01 * v01.x + w10 * v10.x + w11 * v11.x;
  r.y = w00 * v00.y + w01 * v01.y + w10 * v10.y + w11 * v11.y;
  r.z = w00 * v00.z + w01 * v01.z + w10 * v10.z + w11 * v11.z;
  r.w = w00 * v00.w + w01 * v01.w + w10 * v10.w + w11 * v11.w;
  short4v h, lo;
  u16 hh, ll;
  splitbf(r.x, hh, ll); h.x = (short)hh; lo.x = (short)ll;
  splitbf(r.y, hh, ll); h.y = (short)hh; lo.y = (short)ll;
  splitbf(r.z, hh, ll); h.z = (short)hh; lo.z = (short)ll;
  splitbf(r.w, hh, ll); h.w = (short)hh; lo.w = (short)ll;
  size_t base = (size_t)ml * Kp + (size_t)k2 * C + c;
  *(short4v*)(Sh + base) = h;
  *(short4v*)(Sl + base) = lo;
}

// ------- scalar variant for layer 1 (C=3, K=27, Kp=32; covers zero padding) -------
__global__ __launch_bounds__(256) void deform_sample_scalar(
    const float* __restrict__ act, const float* __restrict__ off,
    u16* __restrict__ Sh, u16* __restrict__ Sl,
    int m0, int Mc, int B, int H, int W, int C, int Kp) {
  int i = blockIdx.x * blockDim.x + threadIdx.x;
  int total = Mc * Kp;
  if (i >= total) return;
  int kp = i % Kp;
  int ml = i / Kp;
  float val = 0.f;
  int K = 9 * C;
  if (kp < K) {
    int c = kp % C; int k2 = kp / C;
    int m = m0 + ml;
    int HW = H * W;
    int b = m / HW; int p = m - b * HW; int y = p / W; int x = p - y * W;
    size_t ob = (size_t)b * 18 * HW + p;
    float dy = off[ob + (size_t)(2 * k2) * HW];
    float dx = off[ob + (size_t)(2 * k2 + 1) * HW];
    float py = (float)(y + k2 / 3 - 1) + dy;
    float px = (float)(x + k2 % 3 - 1) + dx;
    float y0f = floorf(py), x0f = floorf(px);
    float wy = py - y0f, wx = px - x0f;
    int iy0 = (int)y0f, ix0 = (int)x0f;
    int iy1 = iy0 + 1, ix1 = ix0 + 1;
    float w00 = (1.f - wy) * (1.f - wx), w01 = (1.f - wy) * wx;
    float w10 = wy * (1.f - wx), w11 = wy * wx;
    if (iy0 < 0 || iy0 >= H) { w00 = 0.f; w01 = 0.f; }
    if (iy1 < 0 || iy1 >= H) { w10 = 0.f; w11 = 0.f; }
    if (ix0 < 0 || ix0 >= W) { w00 = 0.f; w10 = 0.f; }
    if (ix1 < 0 || ix1 >= W) { w01 = 0.f; w11 = 0.f; }
    int cy0 = min(max(iy0, 0), H - 1), cy1 = min(max(iy1, 0), H - 1);
    int cx0 = min(max(ix0, 0), W - 1), cx1 = min(max(ix1, 0), W - 1);
    size_t rowb = (size_t)b * HW;
    float v00 = act[(rowb + cy0 * W + cx0) * C + c];
    float v01 = act[(rowb + cy0 * W + cx1) * C + c];
    float v10 = act[(rowb + cy1 * W + cx0) * C + c];
    float v11 = act[(rowb + cy1 * W + cx1) * C + c];
    val = w00 * v00 + w01 * v01 + w10 * v10 + w11 * v11;
  }
  u16 hh, ll; splitbf(val, hh, ll);
  size_t base = (size_t)ml * Kp + kp;
  Sh[base] = hh; Sl[base] = ll;
}

// ---------------- 4-wave tiled MFMA GEMM (bf16x3), double-buffered LDS ----------------
// 64x64 tile, BK=32, register-staged async prefetch, 1 barrier per k-step.
// A: bf16 hi/lo [M][Kp], B: bf16 hi/lo [N][Kp]. M,N multiples of 64, Kp multiple of 32.
#define LDA 40  // u16 units per LDS row (32 data + 8 pad -> 2-way bank alias only)

__global__ __launch_bounds__(256) void mfma_gemm_tiled(
    const u16* __restrict__ Ah, const u16* __restrict__ Al,
    const u16* __restrict__ Bh, const u16* __restrict__ Bl,
    float* __restrict__ Cf, int M, int N, int Kp, int kPerZ, int atomicMode) {
  __shared__ __align__(16) u16 lds[2 * 4 * 64 * LDA];
  const int TS = 64 * LDA;   // one 64x32 tile
  const int BS = 4 * TS;     // one buffer: Ah,Al,Bh,Bl tiles
  int tid = threadIdx.x;
  int lane = tid & 63, wave = tid >> 6;
  int l15 = lane & 15, quad = lane >> 4;
  int wr = wave >> 1, wc = wave & 1;
  int m0 = blockIdx.x * 64, n0 = blockIdx.y * 64;
  int kStart = blockIdx.z * kPerZ;
  int kEnd = min(Kp, kStart + kPerZ);
  int nSteps = (kEnd - kStart) >> 5;   // multiple-of-32 span, >= 1

  // staging: thread t loads 16B of row (t>>2), k-chunk ((t&3)*8) for each of 4 tiles
  int sr = tid >> 2, sc = (tid & 3) << 3;
  const u16* gAh = Ah + (size_t)(m0 + sr) * Kp + kStart + sc;
  const u16* gAl = Al + (size_t)(m0 + sr) * Kp + kStart + sc;
  const u16* gBh = Bh + (size_t)(n0 + sr) * Kp + kStart + sc;
  const u16* gBl = Bl + (size_t)(n0 + sr) * Kp + kStart + sc;
  int soff = sr * LDA + sc;

  f32x4 z4 = {0.f, 0.f, 0.f, 0.f};
  f32x4 acc00 = z4, acc01 = z4, acc10 = z4, acc11 = z4;

  {  // prologue: stage step 0 into buffer 0
    short8 a = *(const short8*)gAh;
    short8 b = *(const short8*)gAl;
    short8 c = *(const short8*)gBh;
    short8 d = *(const short8*)gBl;
    *(short8*)&lds[0 * TS + soff] = a;
    *(short8*)&lds[1 * TS + soff] = b;
    *(short8*)&lds[2 * TS + soff] = c;
    *(short8*)&lds[3 * TS + soff] = d;
  }
  __syncthreads();

  int raoff = (wr * 32 + l15) * LDA + quad * 8;
  int rboff = (wc * 32 + l15) * LDA + quad * 8;

  for (int i = 0; i < nSteps; ++i) {
    int cb = (i & 1) * BS;
    bool hasNext = (i + 1 < nSteps);
    short8 nA, nB, nC, nD;
    if (hasNext) {  // issue next-step global loads early (hide under MFMAs)
      int kn = (i + 1) << 5;
      nA = *(const short8*)(gAh + kn);
      nB = *(const short8*)(gAl + kn);
      nC = *(const short8*)(gBh + kn);
      nD = *(const short8*)(gBl + kn);
    }
    short8 ah0 = *(const short8*)&lds[cb + 0 * TS + raoff];
    short8 ah1 = *(const short8*)&lds[cb + 0 * TS + raoff + 16 * LDA];
    short8 al0 = *(const short8*)&lds[cb + 1 * TS + raoff];
    short8 al1 = *(const short8*)&lds[cb + 1 * TS + raoff + 16 * LDA];
    short8 bh0 = *(const short8*)&lds[cb + 2 * TS + rboff];
    short8 bh1 = *(const short8*)&lds[cb + 2 * TS + rboff + 16 * LDA];
    short8 bl0 = *(const short8*)&lds[cb + 3 * TS + rboff];
    short8 bl1 = *(const short8*)&lds[cb + 3 * TS + rboff + 16 * LDA];
    acc00 = __builtin_amdgcn_mfma_f32_16x16x32_bf16(ah0, bh0, acc00, 0, 0, 0);
    acc01 = __builtin_amdgcn_mfma_f32_16x16x32_bf16(ah0, bh1, acc01, 0, 0, 0);
    acc10 = __builtin_amdgcn_mfma_f32_16x16x32_bf16(ah1, bh0, acc10, 0, 0, 0);
    acc11 = __builtin_amdgcn_mfma_f32_16x16x32_bf16(ah1, bh1, acc11, 0, 0, 0);
    acc00 = __builtin_amdgcn_mfma_f32_16x16x32_bf16(ah0, bl0, acc00, 0, 0, 0);
    acc01 = __builtin_amdgcn_mfma_f32_16x16x32_bf16(ah0, bl1, acc01, 0, 0, 0);
    acc10 = __builtin_amdgcn_mfma_f32_16x16x32_bf16(ah1, bl0, acc10, 0, 0, 0);
    acc11 = __builtin_amdgcn_mfma_f32_16x16x32_bf16(ah1, bl1, acc11, 0, 0, 0);
    acc00 = __builtin_amdgcn_mfma_f32_16x16x32_bf16(al0, bh0, acc00, 0, 0, 0);
    acc01 = __builtin_amdgcn_mfma_f32_16x16x32_bf16(al0, bh1, acc01, 0, 0, 0);
    acc10 = __builtin_amdgcn_mfma_f32_16x16x32_bf16(al1, bh0, acc10, 0, 0, 0);
    acc11 = __builtin_amdgcn_mfma_f32_16x16x32_bf16(al1, bh1, acc11, 0, 0, 0);
    if (hasNext) {
      int ob = cb ^ BS;
      *(short8*)&lds[ob + 0 * TS + soff] = nA;
      *(short8*)&lds[ob + 1 * TS + soff] = nB;
      *(short8*)&lds[ob + 2 * TS + soff] = nC;
      *(short8*)&lds[ob + 3 * TS + soff] = nD;
      __syncthreads();
    }
  }

  f32x4 av[2][2] = {{acc00, acc01}, {acc10, acc11}};
#pragma unroll
  for (int t = 0; t < 2; ++t) {
    int mB = m0 + wr * 32 + t * 16 + (quad << 2);
#pragma unroll
    for (int u = 0; u < 2; ++u) {
      int n = n0 + wc * 32 + u * 16 + l15;
      f32x4 a = av[t][u];
#pragma unroll
      for (int reg = 0; reg < 4; ++reg) {
        int m = mB + reg;
        if (atomicMode) atomicAdd(&Cf[(size_t)m * N + n], a[reg]);
        else Cf[(size_t)m * N + n] = a[reg];
      }
    }
  }
}

// ---------------- FC variant: A bf16 pair, B fp32 row-major (split in-kernel) ----------------
// Always split-K/atomic (output pre-zeroed). Guards B rows >= N (FC3 N=100).
__global__ __launch_bounds__(64) void mfma_gemm_fc(
    const u16* __restrict__ Ah, const u16* __restrict__ Al,
    const float* __restrict__ Bw, float* __restrict__ Cf,
    int M, int N, int K, int kPerZ) {
  int lane = threadIdx.x;
  int l15 = lane & 15, quad = lane >> 4;
  int m0 = blockIdx.x * 32, n0 = blockIdx.y * 32;
  int kStart = blockIdx.z * kPerZ;
  int kEnd = min(K, kStart + kPerZ);
  f32x4 z4 = {0.f, 0.f, 0.f, 0.f};
  f32x4 acc00 = z4, acc01 = z4, acc10 = z4, acc11 = z4;
  int nr0 = n0 + l15, nr1 = n0 + 16 + l15;
  bool v0 = nr0 < N, v1 = nr1 < N;
  const float* pb0 = Bw + (size_t)(v0 ? nr0 : 0) * K + (quad << 3);
  const float* pb1 = Bw + (size_t)(v1 ? nr1 : 0) * K + (quad << 3);
  const u16* pa0 = Ah + (size_t)(m0 + l15) * K + (quad << 3);
  const u16* pa1 = pa0 + (size_t)16 * K;
  const u16* qa0 = Al + (size_t)(m0 + l15) * K + (quad << 3);
  const u16* qa1 = qa0 + (size_t)16 * K;
  for (int k0 = kStart; k0 < kEnd; k0 += 32) {
    short8 ah0 = *(const short8*)(pa0 + k0);
    short8 ah1 = *(const short8*)(pa1 + k0);
    short8 al0 = *(const short8*)(qa0 + k0);
    short8 al1 = *(const short8*)(qa1 + k0);
    float4 x0 = *(const float4*)(pb0 + k0);
    float4 x1 = *(const float4*)(pb0 + k0 + 4);
    float4 y0 = *(const float4*)(pb1 + k0);
    float4 y1 = *(const float4*)(pb1 + k0 + 4);
    float f0[8] = {x0.x, x0.y, x0.z, x0.w, x1.x, x1.y, x1.z, x1.w};
    float f1[8] = {y0.x, y0.y, y0.z, y0.w, y1.x, y1.y, y1.z, y1.w};
    if (!v0) {
#pragma unroll
      for (int j = 0; j < 8; ++j) f0[j] = 0.f;
    }
    if (!v1) {
#pragma unroll
      for (int j = 0; j < 8; ++j) f1[j] = 0.f;
    }
    VecU bh0u, bl0u, bh1u, bl1u;
#pragma unroll
    for (int j = 0; j < 8; ++j) {
      splitbf(f0[j], bh0u.u[j], bl0u.u[j]);
      splitbf(f1[j], bh1u.u[j], bl1u.u[j]);
    }
    acc00 = __builtin_amdgcn_mfma_f32_16x16x32_bf16(ah0, bh0u.s, acc00, 0, 0, 0);
    acc01 = __builtin_amdgcn_mfma_f32_16x16x32_bf16(ah0, bh1u.s, acc01, 0, 0, 0);
    acc10 = __builtin_amdgcn_mfma_f32_16x16x32_bf16(ah1, bh0u.s, acc10, 0, 0, 0);
    acc11 = __builtin_amdgcn_mfma_f32_16x16x32_bf16(ah1, bh1u.s, acc11, 0, 0, 0);
    acc00 = __builtin_amdgcn_mfma_f32_16x16x32_bf16(ah0, bl0u.s, acc00, 0, 0, 0);
    acc01 = __builtin_amdgcn_mfma_f32_16x16x32_bf16(ah0, bl1u.s, acc01, 0, 0, 0);
    acc10 = __builtin_amdgcn_mfma_f32_16x16x32_bf16(ah1, bl0u.s, acc10, 0, 0, 0);
    acc11 = __builtin_amdgcn_mfma_f32_16x16x32_bf16(ah1, bl1u.s, acc11, 0, 0, 0);
    acc00 = __builtin_amdgcn_mfma_f32_16x16x32_bf16(al0, bh0u.s, acc00, 0, 0, 0);
    acc01 = __builtin_amdgcn_mfma_f32_16x16x32_bf16(al0, bh1u.s, acc01, 0, 0, 0);
    acc10 = __builtin_amdgcn_mfma_f32_16x16x32_bf16(al1, bh0u.s, acc10, 0, 0, 0);
    acc11 = __builtin_amdgcn_mfma_f32_16x16x32_bf16(al1, bh1u.s, acc11, 0, 0, 0);
  }
  f32x4 av[2][2] = {{acc00, acc01}, {acc10, acc11}};
#pragma unroll
  for (int t = 0; t < 2; ++t) {
    int mB = m0 + t * 16 + (quad << 2);
#pragma unroll
    for (int u = 0; u < 2; ++u) {
      int n = n0 + u * 16 + l15;
      if (n >= N) continue;
      f32x4 a = av[t][u];
#pragma unroll
      for (int reg = 0; reg < 4; ++reg) {
        int m = mB + reg;
        if (m >= M) continue;
        atomicAdd(&Cf[(size_t)m * N + n], a[reg]);
      }
    }
  }
}

// ---------------- bias (+optional relu) pass ----------------
__global__ void bias_act_kernel(float* __restrict__ x, const float* __restrict__ bias,
                                int total, int C, int relu) {
  int i = blockIdx.x * blockDim.x + threadIdx.x;
  if (i >= total) return;
  float v = x[i] + bias[i % C];
  if (relu && v < 0.f) v = 0.f;
  x[i] = v;
}

// ---------------- BN batch stats ----------------
__global__ __launch_bounds__(256) void bn_stats_kernel(const float* __restrict__ x,
                                                       float* __restrict__ st,
                                                       int M, int C, int rowsPerBlock) {
  __shared__ float sh[512];
  int t = threadIdx.x;
  int r0 = blockIdx.x * rowsPerBlock;
  int r1 = min(M, r0 + rowsPerBlock);
  if (C >= 256) {
    for (int c = t; c < C; c += 256) {
      float s = 0.f, ss = 0.f;
      for (int r = r0; r < r1; ++r) {
        float v = x[(size_t)r * C + c];
        s += v; ss += v * v;
      }
      atomicAdd(&st[c], s); atomicAdd(&st[512 + c], ss);
    }
  } else {
    int rpb = 256 / C;
    int c = t % C; int ro = t / C;
    float s = 0.f, ss = 0.f;
    for (int r = r0 + ro; r < r1; r += rpb) {
      float v = x[(size_t)r * C + c];
      s += v; ss += v * v;
    }
    sh[t] = s; sh[256 + t] = ss;
    __syncthreads();
    if (ro == 0) {
      for (int k = 1; k < rpb; ++k) { s += sh[k * C + c]; ss += sh[256 + k * C + c]; }
      atomicAdd(&st[c], s); atomicAdd(&st[512 + c], ss);
    }
  }
}

__global__ void bn_finalize_kernel(float* __restrict__ st, const float* __restrict__ g,
                                   const float* __restrict__ bb, int M, int C) {
  int c = threadIdx.x;
  if (c >= C) return;
  float mean = st[c] / (float)M;
  float var = st[512 + c] / (float)M - mean * mean;
  if (var < 0.f) var = 0.f;
  float inv = 1.0f / sqrtf(var + 1e-5f);
  float sc = g[c] * inv;
  st[1024 + c] = sc;
  st[1536 + c] = bb[c] - mean * sc;
}

// -------- permuted 2x2 max pool with fused BN+ReLU on inputs --------
__global__ void pool_kernel(const float* __restrict__ in, const float* __restrict__ stp,
                            float* __restrict__ out,
                            const int* __restrict__ perm, const int* __restrict__ nperm,
                            int B, int H, int C, int total) {
  int i = blockIdx.x * blockDim.x + threadIdx.x;
  if (i >= total) return;
  int oH = H / 2; int oHW = oH * oH; int HW = H * H;
  int c = i % C; int j = (i / C) % oHW; int b = i / (C * oHW);
  float sc = stp[c], sh = stp[512 + c];
  int q = min(max(nperm[j], 0), oHW - 1);
  int qy = q / oH, qx = q % oH;
  float m = 0.f;  // post-ReLU values are >= 0
#pragma unroll
  for (int dy = 0; dy < 2; ++dy)
#pragma unroll
    for (int dx = 0; dx < 2; ++dx) {
      int p = min(max(perm[(2 * qy + dy) * H + (2 * qx + dx)], 0), HW - 1);
      float v = in[((size_t)b * HW + p) * C + c];
      v = fmaxf(v * sc + sh, 0.f);
      m = fmaxf(m, v);
    }
  out[((size_t)b * oHW + j) * C + c] = m;
}

// target >= 512 four-wave blocks (~8 waves/CU); kPerZ multiple of 32
static inline void pick_split4(int gx, int gy, int Kp, int& zs, int& kPerZ) {
  int gxy = gx * gy;
  zs = 1;
  if (gxy < 512) {
    zs = (512 + gxy - 1) / gxy;
    int maxz = Kp / 32; if (maxz < 1) maxz = 1;
    if (zs > maxz) zs = maxz;
  }
  kPerZ = (((Kp + zs - 1) / zs) + 31) & ~31;
  zs = (Kp + kPerZ - 1) / kPerZ;
}

// target >= 1536 one-wave blocks for the FC kernel
static inline void pick_split(int gx, int gy, int Kp, int& zs, int& kPerZ) {
  int gxy = gx * gy;
  zs = 1;
  if (gxy < 1536) {
    zs = (1536 + gxy - 1) / gxy;
    int maxz = Kp / 32; if (maxz < 1) maxz = 1;
    if (zs > maxz) zs = maxz;
  }
  kPerZ = (((Kp + zs - 1) / zs) + 31) & ~31;
  zs = (Kp + kPerZ - 1) / kPerZ;
}

extern "C" void kernel_launch(void* const* d_in, const int* in_sizes, int n_in,
                              void* d_out, int out_size, void* d_ws, size_t ws_size,
                              hipStream_t stream) {
  const int Ci[13]  = {3, 64, 64, 128, 128, 256, 256, 256, 512, 512, 512, 512, 512};
  const int CoA[13] = {64, 64, 128, 128, 256, 256, 256, 512, 512, 512, 512, 512, 512};
  const int Rr[13]  = {32, 32, 16, 16, 8, 8, 8, 4, 4, 4, 2, 2, 2};
  const int poolAfter[13] = {-1, 0, -1, 1, -1, -1, 2, -1, -1, 3, -1, -1, 4};
  const int B = 32;

  size_t cursor = 0;
  auto alloc = [&](size_t bytes) {
    void* p = (char*)d_ws + cursor;
    cursor += (bytes + 255) & ~(size_t)255;
    return p;
  };
  float* stats = (float*)alloc((size_t)13 * 2048 * 4);
  float* fcA   = (float*)alloc((size_t)32 * 4096 * 4);
  u16*   fcPh  = (u16*)alloc((size_t)32 * 4096 * 2);
  u16*   fcPl  = (u16*)alloc((size_t)32 * 4096 * 2);
  float* A0    = (float*)alloc((size_t)2097152 * 4);   // 32768*64 fp32
  float* A1    = (float*)alloc((size_t)2097152 * 4);
  u16*   WTh   = (u16*)alloc((size_t)2359296 * 2);     // 512*4608 bf16 hi
  u16*   WTl   = (u16*)alloc((size_t)2359296 * 2);     // 512*4608 bf16 lo
  size_t remainBytes = (ws_size > cursor) ? (ws_size - cursor) : 0;
  size_t sElems = remainBytes / 4;                     // split across Sh+Sl (2B each)
  if (sElems > (size_t)8388608) sElems = 8388608;      // cap: 16MB per array
  if (sElems < (size_t)589824)  sElems = 589824;       // floor: 128 rows x K=4608
  u16* Sh = (u16*)alloc(sElems * 2);
  u16* Sl = (u16*)alloc(sElems * 2);
  (void)in_sizes; (void)n_in; (void)out_size;

  hipMemsetAsync(stats, 0, (size_t)13 * 2048 * 4, stream);

  {
    int total = B * 3 * 1024;
    nchw2nhwc_kernel<<<(total + 255) / 256, 256, 0, stream>>>(
        (const float*)d_in[0], A0, B, 3, 1024);
  }

  float* cur = A0;
  float* oth = A1;
  int needBN = 0;
  float* stp = nullptr;

  for (int l = 0; l < 13; ++l) {
    int C = Ci[l], N = CoA[l], H = Rr[l];
    int M = B * H * H, K = 9 * C, Kp = (K + 31) & ~31;
    const float* offp = (const float*)d_in[1 + l * 5 + 0];
    const float* wp   = (const float*)d_in[1 + l * 5 + 1];
    const float* gp   = (const float*)d_in[1 + l * 5 + 3];
    const float* bbp  = (const float*)d_in[1 + l * 5 + 4];
    float* st = stats + (size_t)l * 2048;

    wtc_kernel<<<(N * Kp + 255) / 256, 256, 0, stream>>>(wp, WTh, WTl, N, C, Kp);

    int MC = (int)((sElems / (size_t)Kp) & ~(size_t)63);
    if (MC < 64) MC = 64;
    if (MC > M) MC = M;
    for (int r0 = 0; r0 < M; r0 += MC) {
      int Mc = min(MC, M - r0);   // M, MC multiples of 64 -> Mc multiple of 64
      if ((C & 3) == 0) {
        int work = Mc * 9 * (C >> 2);
        deform_sample_v2<<<(work + 255) / 256, 256, 0, stream>>>(
            cur, stp, needBN, offp, Sh, Sl, r0, Mc, B, H, H, C, Kp);
      } else {
        int work = Mc * Kp;
        deform_sample_scalar<<<(work + 255) / 256, 256, 0, stream>>>(
            cur, offp, Sh, Sl, r0, Mc, B, H, H, C, Kp);
      }
      int gx = Mc / 64, gy = N / 64;
      int zs, kPerZ;
      pick_split4(gx, gy, Kp, zs, kPerZ);
      if (zs > 1)
        hipMemsetAsync(oth + (size_t)r0 * N, 0, (size_t)Mc * N * 4, stream);
      mfma_gemm_tiled<<<dim3(gx, gy, zs), 256, 0, stream>>>(
          Sh, Sl, WTh, WTl, oth + (size_t)r0 * N, Mc, N, Kp, kPerZ, zs > 1 ? 1 : 0);
    }

    int rowsPer = 64;
    bn_stats_kernel<<<(M + rowsPer - 1) / rowsPer, 256, 0, stream>>>(oth, st, M, N, rowsPer);
    bn_finalize_kernel<<<1, 512, 0, stream>>>(st, gp, bbp, M, N);

    if (poolAfter[l] >= 0) {
      int pi = poolAfter[l];
      const int* perm  = (const int*)d_in[66 + pi * 2];
      const int* nperm = (const int*)d_in[66 + pi * 2 + 1];
      int oH = H / 2;
      int total = B * oH * oH * N;
      pool_kernel<<<(total + 255) / 256, 256, 0, stream>>>(oth, st + 1024, cur,
                                                           perm, nperm, B, H, N, total);
      needBN = 0; stp = nullptr;
    } else {
      float* t = cur; cur = oth; oth = t;
      needBN = 1; stp = st + 1024;
    }
  }

  // FC head: cur = [32, 512] fp32 (BN+ReLU applied by final pool)
  const float* fw1 = (const float*)d_in[76]; const float* fb1 = (const float*)d_in[77];
  const float* fw2 = (const float*)d_in[78]; const float* fb2 = (const float*)d_in[79];
  const float* fw3 = (const float*)d_in[80]; const float* fb3 = (const float*)d_in[81];
  {
    int zs, kPerZ;
    // conv output -> bf16 pair
    act_convert<<<(32 * 512 + 255) / 256, 256, 0, stream>>>(
        cur, nullptr, 0, fcPh, fcPl, 32 * 512, 512);
    // FC1: 32x4096x512
    hipMemsetAsync(fcA, 0, (size_t)32 * 4096 * 4, stream);
    pick_split(1, 128, 512, zs, kPerZ);
    mfma_gemm_fc<<<dim3(1, 128, zs), 64, 0, stream>>>(fcPh, fcPl, fw1, fcA,
                                                      32, 4096, 512, kPerZ);
    act_convert<<<(32 * 4096 + 255) / 256, 256, 0, stream>>>(
        fcA, fb1, 1, fcPh, fcPl, 32 * 4096, 4096);
    // FC2: 32x4096x4096
    hipMemsetAsync(fcA, 0, (size_t)32 * 4096 * 4, stream);
    pick_split(1, 128, 4096, zs, kPerZ);
    mfma_gemm_fc<<<dim3(1, 128, zs), 64, 0, stream>>>(fcPh, fcPl, fw2, fcA,
                                                      32, 4096, 4096, kPerZ);
    act_convert<<<(32 * 4096 + 255) / 256, 256, 0, stream>>>(
        fcA, fb2, 1, fcPh, fcPl, 32 * 4096, 4096);
    // FC3: 32x100x4096
    hipMemsetAsync(d_out, 0, (size_t)3200 * 4, stream);
    pick_split(1, 4, 4096, zs, kPerZ);
    mfma_gemm_fc<<<dim3(1, 4, zs), 64, 0, stream>>>(fcPh, fcPl, fw3, (float*)d_out,
                                                    32, 100, 4096, kPerZ);
    bias_act_kernel<<<(3200 + 255) / 256, 256, 0, stream>>>((float*)d_out, fb3, 3200, 100, 0);
  }
}

// Round 3
// 1092.103 us; speedup vs baseline: 1.2321x; 1.0621x over previous
//
#include <hip/hip_runtime.h>
#include <hip/hip_bf16.h>

typedef __hip_bfloat16 bf16;
typedef __attribute__((ext_vector_type(8))) short short8;
typedef __attribute__((ext_vector_type(4))) short short4v;
typedef __attribute__((ext_vector_type(4))) float f32x4;
typedef unsigned short u16;
#define BF2F(x) __bfloat162float(x)

__device__ __forceinline__ u16 f2bfbits(float v) {
  bf16 h = __float2bfloat16(v);
  return *(u16*)&h;
}
__device__ __forceinline__ float bfbits2f(u16 u) {
  bf16 h; *(u16*)&h = u;
  return BF2F(h);
}
__device__ __forceinline__ void splitbf(float v, u16& hi, u16& lo) {
  hi = f2bfbits(v);
  lo = f2bfbits(v - bfbits2f(hi));
}

union VecU {
  u16 u[8];
  short8 s;
};

// ---------------- NCHW(f32) -> NHWC(f32) ----------------
__global__ void nchw2nhwc_kernel(const float* __restrict__ in, float* __restrict__ out,
                                 int B, int C, int HW) {
  int i = blockIdx.x * blockDim.x + threadIdx.x;
  int total = B * C * HW;
  if (i >= total) return;
  int c = i % C; int p = (i / C) % HW; int b = i / (C * HW);
  out[i] = in[((size_t)b * C + c) * HW + p];
}

// ------- conv weight: w[co][ci][k2] -> bf16 hi/lo [co][k2*C+ci], zero-padded to Kp -------
__global__ void wtc_kernel(const float* __restrict__ w, u16* __restrict__ Wh,
                           u16* __restrict__ Wl, int N, int C, int Kp) {
  int i = blockIdx.x * blockDim.x + threadIdx.x;
  if (i >= N * Kp) return;
  int k = i % Kp; int co = i / Kp;
  int K = 9 * C;
  float v = 0.f;
  if (k < K) {
    int ci = k % C; int k2 = k / C;
    v = w[((size_t)co * C + ci) * 9 + k2];
  }
  u16 hh, ll; splitbf(v, hh, ll);
  Wh[i] = hh; Wl[i] = ll;
}

// ------- fp32 activations (+opt bias+relu) -> bf16 hi/lo pair -------
__global__ void act_convert(const float* __restrict__ x, const float* __restrict__ bias,
                            int relu, u16* __restrict__ Ah, u16* __restrict__ Al,
                            int total, int Cc) {
  int i = blockIdx.x * blockDim.x + threadIdx.x;
  if (i >= total) return;
  float v = x[i];
  if (bias) v += bias[i % Cc];
  if (relu && v < 0.f) v = 0.f;
  u16 hh, ll; splitbf(v, hh, ll);
  Ah[i] = hh; Al[i] = ll;
}

// ------- flattened deformable sampling: thread = (pixel, k2, c4-chunk) -------
// fused BN(scale/shift)+ReLU on gathered values; writes bf16 hi/lo pair
__global__ __launch_bounds__(256) void deform_sample_v2(
    const float* __restrict__ act, const float* __restrict__ stp, int bnmode,
    const float* __restrict__ off, u16* __restrict__ Sh, u16* __restrict__ Sl,
    int m0, int Mc, int B, int H, int W, int C, int Kp) {
  int i = blockIdx.x * blockDim.x + threadIdx.x;
  int c4n = C >> 2;
  int total = Mc * 9 * c4n;
  if (i >= total) return;
  int c4 = i % c4n;
  int t = i / c4n;
  int k2 = t % 9;
  int ml = t / 9;
  int m = m0 + ml;
  int HW = H * W;
  int b = m / HW; int p = m - b * HW; int y = p / W; int x = p - y * W;
  size_t ob = (size_t)b * 18 * HW + p;
  float dy = off[ob + (size_t)(2 * k2) * HW];
  float dx = off[ob + (size_t)(2 * k2 + 1) * HW];
  float py = (float)(y + k2 / 3 - 1) + dy;
  float px = (float)(x + k2 % 3 - 1) + dx;
  float y0f = floorf(py), x0f = floorf(px);
  float wy = py - y0f, wx = px - x0f;
  int iy0 = (int)y0f, ix0 = (int)x0f;
  int iy1 = iy0 + 1, ix1 = ix0 + 1;
  float w00 = (1.f - wy) * (1.f - wx), w01 = (1.f - wy) * wx;
  float w10 = wy * (1.f - wx), w11 = wy * wx;
  if (iy0 < 0 || iy0 >= H) { w00 = 0.f; w01 = 0.f; }
  if (iy1 < 0 || iy1 >= H) { w10 = 0.f; w11 = 0.f; }
  if (ix0 < 0 || ix0 >= W) { w00 = 0.f; w10 = 0.f; }
  if (ix1 < 0 || ix1 >= W) { w01 = 0.f; w11 = 0.f; }
  int cy0 = min(max(iy0, 0), H - 1), cy1 = min(max(iy1, 0), H - 1);
  int cx0 = min(max(ix0, 0), W - 1), cx1 = min(max(ix1, 0), W - 1);
  int c = c4 << 2;
  size_t rowb = (size_t)b * HW;
  float4 v00 = *(const float4*)(act + (rowb + cy0 * W + cx0) * C + c);
  float4 v01 = *(const float4*)(act + (rowb + cy0 * W + cx1) * C + c);
  float4 v10 = *(const float4*)(act + (rowb + cy1 * W + cx0) * C + c);
  float4 v11 = *(const float4*)(act + (rowb + cy1 * W + cx1) * C + c);
  if (bnmode) {
    float4 sc = *(const float4*)(stp + c);
    float4 sh = *(const float4*)(stp + 512 + c);
    v00.x = fmaxf(v00.x * sc.x + sh.x, 0.f); v00.y = fmaxf(v00.y * sc.y + sh.y, 0.f);
    v00.z = fmaxf(v00.z * sc.z + sh.z, 0.f); v00.w = fmaxf(v00.w * sc.w + sh.w, 0.f);
    v01.x = fmaxf(v01.x * sc.x + sh.x, 0.f); v01.y = fmaxf(v01.y * sc.y + sh.y, 0.f);
    v01.z = fmaxf(v01.z * sc.z + sh.z, 0.f); v01.w = fmaxf(v01.w * sc.w + sh.w, 0.f);
    v10.x = fmaxf(v10.x * sc.x + sh.x, 0.f); v10.y = fmaxf(v10.y * sc.y + sh.y, 0.f);
    v10.z = fmaxf(v10.z * sc.z + sh.z, 0.f); v10.w = fmaxf(v10.w * sc.w + sh.w, 0.f);
    v11.x = fmaxf(v11.x * sc.x + sh.x, 0.f); v11.y = fmaxf(v11.y * sc.y + sh.y, 0.f);
    v11.z = fmaxf(v11.z * sc.z + sh.z, 0.f); v11.w = fmaxf(v11.w * sc.w + sh.w, 0.f);
  }
  float4 r;
  r.x = w00 * v00.x + w01 * v01.x + w10 * v10.x + w11 * v11.x;
  r.y = w00 * v00.y + w01 * v01.y + w10 * v10.y + w11 * v11.y;
  r.z = w00 * v00.z + w01 * v01.z + w10 * v10.z + w11 * v11.z;
  r.w = w00 * v00.w + w01 * v01.w + w10 * v10.w + w11 * v11.w;
  short4v h, lo;
  u16 hh, ll;
  splitbf(r.x, hh, ll); h.x = (short)hh; lo.x = (short)ll;
  splitbf(r.y, hh, ll); h.y = (short)hh; lo.y = (short)ll;
  splitbf(r.z, hh, ll); h.z = (short)hh; lo.z = (short)ll;
  splitbf(r.w, hh, ll); h.w = (short)hh; lo.w = (short)ll;
  size_t base = (size_t)ml * Kp + (size_t)k2 * C + c;
  *(short4v*)(Sh + base) = h;
  *(short4v*)(Sl + base) = lo;
}

// ------- scalar variant for layer 1 (C=3, K=27, Kp=32; covers zero padding) -------
__global__ __launch_bounds__(256) void deform_sample_scalar(
    const float* __restrict__ act, const float* __restrict__ off,
    u16* __restrict__ Sh, u16* __restrict__ Sl,
    int m0, int Mc, int B, int H, int W, int C, int Kp) {
  int i = blockIdx.x * blockDim.x + threadIdx.x;
  int total = Mc * Kp;
  if (i >= total) return;
  int kp = i % Kp;
  int ml = i / Kp;
  float val = 0.f;
  int K = 9 * C;
  if (kp < K) {
    int c = kp % C; int k2 = kp / C;
    int m = m0 + ml;
    int HW = H * W;
    int b = m / HW; int p = m - b * HW; int y = p / W; int x = p - y * W;
    size_t ob = (size_t)b * 18 * HW + p;
    float dy = off[ob + (size_t)(2 * k2) * HW];
    float dx = off[ob + (size_t)(2 * k2 + 1) * HW];
    float py = (float)(y + k2 / 3 - 1) + dy;
    float px = (float)(x + k2 % 3 - 1) + dx;
    float y0f = floorf(py), x0f = floorf(px);
    float wy = py - y0f, wx = px - x0f;
    int iy0 = (int)y0f, ix0 = (int)x0f;
    int iy1 = iy0 + 1, ix1 = ix0 + 1;
    float w00 = (1.f - wy) * (1.f - wx), w01 = (1.f - wy) * wx;
    float w10 = wy * (1.f - wx), w11 = wy * wx;
    if (iy0 < 0 || iy0 >= H) { w00 = 0.f; w01 = 0.f; }
    if (iy1 < 0 || iy1 >= H) { w10 = 0.f; w11 = 0.f; }
    if (ix0 < 0 || ix0 >= W) { w00 = 0.f; w10 = 0.f; }
    if (ix1 < 0 || ix1 >= W) { w01 = 0.f; w11 = 0.f; }
    int cy0 = min(max(iy0, 0), H - 1), cy1 = min(max(iy1, 0), H - 1);
    int cx0 = min(max(ix0, 0), W - 1), cx1 = min(max(ix1, 0), W - 1);
    size_t rowb = (size_t)b * HW;
    float v00 = act[(rowb + cy0 * W + cx0) * C + c];
    float v01 = act[(rowb + cy0 * W + cx1) * C + c];
    float v10 = act[(rowb + cy1 * W + cx0) * C + c];
    float v11 = act[(rowb + cy1 * W + cx1) * C + c];
    val = w00 * v00 + w01 * v01 + w10 * v10 + w11 * v11;
  }
  u16 hh, ll; splitbf(val, hh, ll);
  size_t base = (size_t)ml * Kp + kp;
  Sh[base] = hh; Sl[base] = ll;
}

// ---------------- 4-wave tiled MFMA GEMM (bf16x3), double-buffered LDS ----------------
// 64x64 tile, BK=32, register-staged async prefetch, 1 barrier per k-step.
#define LDA 40  // u16 units per LDS row (32 data + 8 pad -> 2-way bank alias only)

__global__ __launch_bounds__(256) void mfma_gemm_tiled(
    const u16* __restrict__ Ah, const u16* __restrict__ Al,
    const u16* __restrict__ Bh, const u16* __restrict__ Bl,
    float* __restrict__ Cf, int M, int N, int Kp, int kPerZ, int atomicMode) {
  __shared__ __align__(16) u16 lds[2 * 4 * 64 * LDA];
  const int TS = 64 * LDA;   // one 64x32 tile
  const int BS = 4 * TS;     // one buffer: Ah,Al,Bh,Bl tiles
  int tid = threadIdx.x;
  int lane = tid & 63, wave = tid >> 6;
  int l15 = lane & 15, quad = lane >> 4;
  int wr = wave >> 1, wc = wave & 1;
  int m0 = blockIdx.x * 64, n0 = blockIdx.y * 64;
  int kStart = blockIdx.z * kPerZ;
  int kEnd = min(Kp, kStart + kPerZ);
  int nSteps = (kEnd - kStart) >> 5;   // multiple-of-32 span, >= 1

  int sr = tid >> 2, sc = (tid & 3) << 3;
  const u16* gAh = Ah + (size_t)(m0 + sr) * Kp + kStart + sc;
  const u16* gAl = Al + (size_t)(m0 + sr) * Kp + kStart + sc;
  const u16* gBh = Bh + (size_t)(n0 + sr) * Kp + kStart + sc;
  const u16* gBl = Bl + (size_t)(n0 + sr) * Kp + kStart + sc;
  int soff = sr * LDA + sc;

  f32x4 z4 = {0.f, 0.f, 0.f, 0.f};
  f32x4 acc00 = z4, acc01 = z4, acc10 = z4, acc11 = z4;

  {  // prologue: stage step 0 into buffer 0
    short8 a = *(const short8*)gAh;
    short8 b = *(const short8*)gAl;
    short8 c = *(const short8*)gBh;
    short8 d = *(const short8*)gBl;
    *(short8*)&lds[0 * TS + soff] = a;
    *(short8*)&lds[1 * TS + soff] = b;
    *(short8*)&lds[2 * TS + soff] = c;
    *(short8*)&lds[3 * TS + soff] = d;
  }
  __syncthreads();

  int raoff = (wr * 32 + l15) * LDA + quad * 8;
  int rboff = (wc * 32 + l15) * LDA + quad * 8;

  for (int i = 0; i < nSteps; ++i) {
    int cb = (i & 1) * BS;
    bool hasNext = (i + 1 < nSteps);
    short8 nA, nB, nC, nD;
    if (hasNext) {
      int kn = (i + 1) << 5;
      nA = *(const short8*)(gAh + kn);
      nB = *(const short8*)(gAl + kn);
      nC = *(const short8*)(gBh + kn);
      nD = *(const short8*)(gBl + kn);
    }
    short8 ah0 = *(const short8*)&lds[cb + 0 * TS + raoff];
    short8 ah1 = *(const short8*)&lds[cb + 0 * TS + raoff + 16 * LDA];
    short8 al0 = *(const short8*)&lds[cb + 1 * TS + raoff];
    short8 al1 = *(const short8*)&lds[cb + 1 * TS + raoff + 16 * LDA];
    short8 bh0 = *(const short8*)&lds[cb + 2 * TS + rboff];
    short8 bh1 = *(const short8*)&lds[cb + 2 * TS + rboff + 16 * LDA];
    short8 bl0 = *(const short8*)&lds[cb + 3 * TS + rboff];
    short8 bl1 = *(const short8*)&lds[cb + 3 * TS + rboff + 16 * LDA];
    acc00 = __builtin_amdgcn_mfma_f32_16x16x32_bf16(ah0, bh0, acc00, 0, 0, 0);
    acc01 = __builtin_amdgcn_mfma_f32_16x16x32_bf16(ah0, bh1, acc01, 0, 0, 0);
    acc10 = __builtin_amdgcn_mfma_f32_16x16x32_bf16(ah1, bh0, acc10, 0, 0, 0);
    acc11 = __builtin_amdgcn_mfma_f32_16x16x32_bf16(ah1, bh1, acc11, 0, 0, 0);
    acc00 = __builtin_amdgcn_mfma_f32_16x16x32_bf16(ah0, bl0, acc00, 0, 0, 0);
    acc01 = __builtin_amdgcn_mfma_f32_16x16x32_bf16(ah0, bl1, acc01, 0, 0, 0);
    acc10 = __builtin_amdgcn_mfma_f32_16x16x32_bf16(ah1, bl0, acc10, 0, 0, 0);
    acc11 = __builtin_amdgcn_mfma_f32_16x16x32_bf16(ah1, bl1, acc11, 0, 0, 0);
    acc00 = __builtin_amdgcn_mfma_f32_16x16x32_bf16(al0, bh0, acc00, 0, 0, 0);
    acc01 = __builtin_amdgcn_mfma_f32_16x16x32_bf16(al0, bh1, acc01, 0, 0, 0);
    acc10 = __builtin_amdgcn_mfma_f32_16x16x32_bf16(al1, bh0, acc10, 0, 0, 0);
    acc11 = __builtin_amdgcn_mfma_f32_16x16x32_bf16(al1, bh1, acc11, 0, 0, 0);
    if (hasNext) {
      int ob = cb ^ BS;
      *(short8*)&lds[ob + 0 * TS + soff] = nA;
      *(short8*)&lds[ob + 1 * TS + soff] = nB;
      *(short8*)&lds[ob + 2 * TS + soff] = nC;
      *(short8*)&lds[ob + 3 * TS + soff] = nD;
      __syncthreads();
    }
  }

  f32x4 av[2][2] = {{acc00, acc01}, {acc10, acc11}};
#pragma unroll
  for (int t = 0; t < 2; ++t) {
    int mB = m0 + wr * 32 + t * 16 + (quad << 2);
#pragma unroll
    for (int u = 0; u < 2; ++u) {
      int n = n0 + wc * 32 + u * 16 + l15;
      f32x4 a = av[t][u];
#pragma unroll
      for (int reg = 0; reg < 4; ++reg) {
        int m = mB + reg;
        if (atomicMode) atomicAdd(&Cf[(size_t)m * N + n], a[reg]);
        else Cf[(size_t)m * N + n] = a[reg];
      }
    }
  }
}

// ---------------- FC: 4-wave, M=32 fixed, B fp32 staged->bf16 pair in LDS ----------------
// Tile 32(M) x 64(N), BK=32, double-buffered B staging, A direct from global.
#define LDAF 40

__global__ __launch_bounds__(256) void mfma_gemm_fc4(
    const u16* __restrict__ Ah, const u16* __restrict__ Al,
    const float* __restrict__ Bw, float* __restrict__ Cf,
    int N, int K, int kPerZ) {
  __shared__ __align__(16) u16 sB[2][2][64 * LDAF];  // [buf][hi/lo]
  int tid = threadIdx.x;
  int lane = tid & 63, wave = tid >> 6;
  int l15 = lane & 15, quad = lane >> 4;
  int wm = wave >> 1, wn = wave & 1;   // wm: 16-row block of M=32; wn: 32-col block
  int n0 = blockIdx.y * 64;
  int kStart = blockIdx.z * kPerZ;
  int kEnd = min(K, kStart + kPerZ);
  int nSteps = (kEnd - kStart) >> 5;

  int sr = tid >> 2, sc = (tid & 3) << 3;
  int gn = n0 + sr; if (gn >= N) gn = 0;   // safe row; extra outputs discarded
  const float* gB = Bw + (size_t)gn * K + kStart + sc;
  int soff = sr * LDAF + sc;

  const u16* pa = Ah + (size_t)(wm * 16 + l15) * K + kStart + (quad << 3);
  const u16* qa = Al + (size_t)(wm * 16 + l15) * K + kStart + (quad << 3);

  f32x4 z4 = {0.f, 0.f, 0.f, 0.f};
  f32x4 acc0 = z4, acc1 = z4;

  {  // prologue stage
    float4 x0 = *(const float4*)gB;
    float4 x1 = *(const float4*)(gB + 4);
    float f[8] = {x0.x, x0.y, x0.z, x0.w, x1.x, x1.y, x1.z, x1.w};
    VecU uh, ul;
#pragma unroll
    for (int j = 0; j < 8; ++j) splitbf(f[j], uh.u[j], ul.u[j]);
    *(short8*)&sB[0][0][soff] = uh.s;
    *(short8*)&sB[0][1][soff] = ul.s;
  }
  __syncthreads();

  int rb0 = (wn * 32 + l15) * LDAF + (quad << 3);
  int rb1 = (wn * 32 + 16 + l15) * LDAF + (quad << 3);

  for (int i = 0; i < nSteps; ++i) {
    int cb = i & 1;
    bool hasNext = (i + 1 < nSteps);
    float4 x0, x1;
    if (hasNext) {
      int kn = (i + 1) << 5;
      x0 = *(const float4*)(gB + kn);
      x1 = *(const float4*)(gB + kn + 4);
    }
    int k0 = i << 5;
    short8 ah = *(const short8*)(pa + k0);
    short8 al = *(const short8*)(qa + k0);
    short8 bh0 = *(const short8*)&sB[cb][0][rb0];
    short8 bh1 = *(const short8*)&sB[cb][0][rb1];
    short8 bl0 = *(const short8*)&sB[cb][1][rb0];
    short8 bl1 = *(const short8*)&sB[cb][1][rb1];
    acc0 = __builtin_amdgcn_mfma_f32_16x16x32_bf16(ah, bh0, acc0, 0, 0, 0);
    acc1 = __builtin_amdgcn_mfma_f32_16x16x32_bf16(ah, bh1, acc1, 0, 0, 0);
    acc0 = __builtin_amdgcn_mfma_f32_16x16x32_bf16(ah, bl0, acc0, 0, 0, 0);
    acc1 = __builtin_amdgcn_mfma_f32_16x16x32_bf16(ah, bl1, acc1, 0, 0, 0);
    acc0 = __builtin_amdgcn_mfma_f32_16x16x32_bf16(al, bh0, acc0, 0, 0, 0);
    acc1 = __builtin_amdgcn_mfma_f32_16x16x32_bf16(al, bh1, acc1, 0, 0, 0);
    if (hasNext) {
      float f[8] = {x0.x, x0.y, x0.z, x0.w, x1.x, x1.y, x1.z, x1.w};
      VecU uh, ul;
#pragma unroll
      for (int j = 0; j < 8; ++j) splitbf(f[j], uh.u[j], ul.u[j]);
      *(short8*)&sB[cb ^ 1][0][soff] = uh.s;
      *(short8*)&sB[cb ^ 1][1][soff] = ul.s;
      __syncthreads();
    }
  }

  f32x4 av[2] = {acc0, acc1};
#pragma unroll
  for (int u = 0; u < 2; ++u) {
    int n = n0 + wn * 32 + u * 16 + l15;
    if (n >= N) continue;
    f32x4 a = av[u];
#pragma unroll
    for (int reg = 0; reg < 4; ++reg) {
      int m = wm * 16 + (quad << 2) + reg;
      atomicAdd(&Cf[(size_t)m * N + n], a[reg]);
    }
  }
}

// ---------------- bias (+optional relu) pass ----------------
__global__ void bias_act_kernel(float* __restrict__ x, const float* __restrict__ bias,
                                int total, int C, int relu) {
  int i = blockIdx.x * blockDim.x + threadIdx.x;
  if (i >= total) return;
  float v = x[i] + bias[i % C];
  if (relu && v < 0.f) v = 0.f;
  x[i] = v;
}

// ---------------- BN batch stats + fused finalize (last block) ----------------
// st layout (stride 2304 floats): [0,512) sum, [512,1024) sumsq,
// [1024,1536) scale, [1536,2048) shift, [2048] completion counter (uint bits)
__global__ __launch_bounds__(256) void bn_stats_fused(
    const float* __restrict__ x, float* __restrict__ st,
    const float* __restrict__ g, const float* __restrict__ bb,
    int M, int C, int rowsPerBlock, int nBlocks) {
  __shared__ float sh[512];
  __shared__ int isLast;
  int t = threadIdx.x;
  int r0 = blockIdx.x * rowsPerBlock;
  int r1 = min(M, r0 + rowsPerBlock);
  if (C >= 256) {
    for (int c = t; c < C; c += 256) {
      float s = 0.f, ss = 0.f;
      for (int r = r0; r < r1; ++r) {
        float v = x[(size_t)r * C + c];
        s += v; ss += v * v;
      }
      atomicAdd(&st[c], s); atomicAdd(&st[512 + c], ss);
    }
  } else {
    int rpb = 256 / C;
    int c = t % C; int ro = t / C;
    float s = 0.f, ss = 0.f;
    for (int r = r0 + ro; r < r1; r += rpb) {
      float v = x[(size_t)r * C + c];
      s += v; ss += v * v;
    }
    sh[t] = s; sh[256 + t] = ss;
    __syncthreads();
    if (ro == 0) {
      for (int k = 1; k < rpb; ++k) { s += sh[k * C + c]; ss += sh[256 + k * C + c]; }
      atomicAdd(&st[c], s); atomicAdd(&st[512 + c], ss);
    }
  }
  __syncthreads();
  if (t == 0) {
    __threadfence();
    unsigned old = atomicAdd((unsigned int*)(st + 2048), 1u);
    isLast = (old == (unsigned)(nBlocks - 1)) ? 1 : 0;
  }
  __syncthreads();
  if (isLast) {
    for (int c = t; c < C; c += 256) {
      float s = atomicAdd(&st[c], 0.f);        // L2-coherent read
      float ss = atomicAdd(&st[512 + c], 0.f);
      float mean = s / (float)M;
      float var = ss / (float)M - mean * mean;
      if (var < 0.f) var = 0.f;
      float inv = 1.0f / sqrtf(var + 1e-5f);
      float scv = g[c] * inv;
      st[1024 + c] = scv;
      st[1536 + c] = bb[c] - mean * scv;
    }
  }
}

// -------- permuted 2x2 max pool with fused BN+ReLU on inputs --------
__global__ void pool_kernel(const float* __restrict__ in, const float* __restrict__ stp,
                            float* __restrict__ out,
                            const int* __restrict__ perm, const int* __restrict__ nperm,
                            int B, int H, int C, int total) {
  int i = blockIdx.x * blockDim.x + threadIdx.x;
  if (i >= total) return;
  int oH = H / 2; int oHW = oH * oH; int HW = H * H;
  int c = i % C; int j = (i / C) % oHW; int b = i / (C * oHW);
  float sc = stp[c], sh = stp[512 + c];
  int q = min(max(nperm[j], 0), oHW - 1);
  int qy = q / oH, qx = q % oH;
  float m = 0.f;  // post-ReLU values are >= 0
#pragma unroll
  for (int dy = 0; dy < 2; ++dy)
#pragma unroll
    for (int dx = 0; dx < 2; ++dx) {
      int p = min(max(perm[(2 * qy + dy) * H + (2 * qx + dx)], 0), HW - 1);
      float v = in[((size_t)b * HW + p) * C + c];
      v = fmaxf(v * sc + sh, 0.f);
      m = fmaxf(m, v);
    }
  out[((size_t)b * oHW + j) * C + c] = m;
}

// target >= 512 four-wave blocks (~8 waves/CU); kPerZ multiple of 32
static inline void pick_split4(int gx, int gy, int Kp, int& zs, int& kPerZ) {
  int gxy = gx * gy;
  zs = 1;
  if (gxy < 512) {
    zs = (512 + gxy - 1) / gxy;
    int maxz = Kp / 32; if (maxz < 1) maxz = 1;
    if (zs > maxz) zs = maxz;
  }
  kPerZ = (((Kp + zs - 1) / zs) + 31) & ~31;
  zs = (Kp + kPerZ - 1) / kPerZ;
}

// FC split: target >= 512 blocks, zs capped at 32 (atomic contention)
static inline void pick_splitFC(int gy, int K, int& zs, int& kPerZ) {
  zs = (512 + gy - 1) / gy;
  int maxz = K / 32; if (maxz < 1) maxz = 1;
  if (zs > maxz) zs = maxz;
  if (zs > 32) zs = 32;
  kPerZ = (((K + zs - 1) / zs) + 31) & ~31;
  zs = (K + kPerZ - 1) / kPerZ;
}

extern "C" void kernel_launch(void* const* d_in, const int* in_sizes, int n_in,
                              void* d_out, int out_size, void* d_ws, size_t ws_size,
                              hipStream_t stream) {
  const int Ci[13]  = {3, 64, 64, 128, 128, 256, 256, 256, 512, 512, 512, 512, 512};
  const int CoA[13] = {64, 64, 128, 128, 256, 256, 256, 512, 512, 512, 512, 512, 512};
  const int Rr[13]  = {32, 32, 16, 16, 8, 8, 8, 4, 4, 4, 2, 2, 2};
  const int poolAfter[13] = {-1, 0, -1, 1, -1, -1, 2, -1, -1, 3, -1, -1, 4};
  const int B = 32;
  const int ST = 2304;   // stats stride (floats)

  size_t cursor = 0;
  auto alloc = [&](size_t bytes) {
    void* p = (char*)d_ws + cursor;
    cursor += (bytes + 255) & ~(size_t)255;
    return p;
  };
  float* stats = (float*)alloc((size_t)13 * ST * 4);
  float* fcA   = (float*)alloc((size_t)32 * 4096 * 4);
  u16*   fcPh  = (u16*)alloc((size_t)32 * 4096 * 2);
  u16*   fcPl  = (u16*)alloc((size_t)32 * 4096 * 2);
  float* A0    = (float*)alloc((size_t)2097152 * 4);   // 32768*64 fp32
  float* A1    = (float*)alloc((size_t)2097152 * 4);
  u16*   WTh   = (u16*)alloc((size_t)2359296 * 2);     // 512*4608 bf16 hi
  u16*   WTl   = (u16*)alloc((size_t)2359296 * 2);     // 512*4608 bf16 lo
  size_t remainBytes = (ws_size > cursor) ? (ws_size - cursor) : 0;
  size_t sElems = remainBytes / 4;                     // Sh+Sl, 2B each
  if (sElems > (size_t)20971520) sElems = 20971520;    // 20M elems: L2 single-chunk
  if (sElems < (size_t)589824)  sElems = 589824;
  u16* Sh = (u16*)alloc(sElems * 2);
  u16* Sl = (u16*)alloc(sElems * 2);
  (void)in_sizes; (void)n_in; (void)out_size;

  hipMemsetAsync(stats, 0, (size_t)13 * ST * 4, stream);

  {
    int total = B * 3 * 1024;
    nchw2nhwc_kernel<<<(total + 255) / 256, 256, 0, stream>>>(
        (const float*)d_in[0], A0, B, 3, 1024);
  }

  float* cur = A0;
  float* oth = A1;
  int needBN = 0;
  float* stp = nullptr;

  for (int l = 0; l < 13; ++l) {
    int C = Ci[l], N = CoA[l], H = Rr[l];
    int M = B * H * H, K = 9 * C, Kp = (K + 31) & ~31;
    const float* offp = (const float*)d_in[1 + l * 5 + 0];
    const float* wp   = (const float*)d_in[1 + l * 5 + 1];
    const float* gp   = (const float*)d_in[1 + l * 5 + 3];
    const float* bbp  = (const float*)d_in[1 + l * 5 + 4];
    float* st = stats + (size_t)l * ST;

    wtc_kernel<<<(N * Kp + 255) / 256, 256, 0, stream>>>(wp, WTh, WTl, N, C, Kp);

    int MC = (int)((sElems / (size_t)Kp) & ~(size_t)63);
    if (MC < 64) MC = 64;
    if (MC > M) MC = M;
    for (int r0 = 0; r0 < M; r0 += MC) {
      int Mc = min(MC, M - r0);   // multiples of 64
      if ((C & 3) == 0) {
        int work = Mc * 9 * (C >> 2);
        deform_sample_v2<<<(work + 255) / 256, 256, 0, stream>>>(
            cur, stp, needBN, offp, Sh, Sl, r0, Mc, B, H, H, C, Kp);
      } else {
        int work = Mc * Kp;
        deform_sample_scalar<<<(work + 255) / 256, 256, 0, stream>>>(
            cur, offp, Sh, Sl, r0, Mc, B, H, H, C, Kp);
      }
      int gx = Mc / 64, gy = N / 64;
      int zs, kPerZ;
      pick_split4(gx, gy, Kp, zs, kPerZ);
      if (zs > 1)
        hipMemsetAsync(oth + (size_t)r0 * N, 0, (size_t)Mc * N * 4, stream);
      mfma_gemm_tiled<<<dim3(gx, gy, zs), 256, 0, stream>>>(
          Sh, Sl, WTh, WTl, oth + (size_t)r0 * N, Mc, N, Kp, kPerZ, zs > 1 ? 1 : 0);
    }

    int rowsPer = 64;
    int nB = (M + rowsPer - 1) / rowsPer;
    bn_stats_fused<<<nB, 256, 0, stream>>>(oth, st, gp, bbp, M, N, rowsPer, nB);

    if (poolAfter[l] >= 0) {
      int pi = poolAfter[l];
      const int* perm  = (const int*)d_in[66 + pi * 2];
      const int* nperm = (const int*)d_in[66 + pi * 2 + 1];
      int oH = H / 2;
      int total = B * oH * oH * N;
      pool_kernel<<<(total + 255) / 256, 256, 0, stream>>>(oth, st + 1024, cur,
                                                           perm, nperm, B, H, N, total);
      needBN = 0; stp = nullptr;
    } else {
      float* t = cur; cur = oth; oth = t;
      needBN = 1; stp = st + 1024;
    }
  }

  // FC head: cur = [32, 512] fp32 (BN+ReLU applied by final pool)
  const float* fw1 = (const float*)d_in[76]; const float* fb1 = (const float*)d_in[77];
  const float* fw2 = (const float*)d_in[78]; const float* fb2 = (const float*)d_in[79];
  const float* fw3 = (const float*)d_in[80]; const float* fb3 = (const float*)d_in[81];
  {
    int zs, kPerZ;
    // conv output -> bf16 pair
    act_convert<<<(32 * 512 + 255) / 256, 256, 0, stream>>>(
        cur, nullptr, 0, fcPh, fcPl, 32 * 512, 512);
    // FC1: 32x4096x512
    hipMemsetAsync(fcA, 0, (size_t)32 * 4096 * 4, stream);
    pick_splitFC(64, 512, zs, kPerZ);
    mfma_gemm_fc4<<<dim3(1, 64, zs), 256, 0, stream>>>(fcPh, fcPl, fw1, fcA,
                                                       4096, 512, kPerZ);
    act_convert<<<(32 * 4096 + 255) / 256, 256, 0, stream>>>(
        fcA, fb1, 1, fcPh, fcPl, 32 * 4096, 4096);
    // FC2: 32x4096x4096
    hipMemsetAsync(fcA, 0, (size_t)32 * 4096 * 4, stream);
    pick_splitFC(64, 4096, zs, kPerZ);
    mfma_gemm_fc4<<<dim3(1, 64, zs), 256, 0, stream>>>(fcPh, fcPl, fw2, fcA,
                                                       4096, 4096, kPerZ);
    act_convert<<<(32 * 4096 + 255) / 256, 256, 0, stream>>>(
        fcA, fb2, 1, fcPh, fcPl, 32 * 4096, 4096);
    // FC3: 32x100x4096
    hipMemsetAsync(d_out, 0, (size_t)3200 * 4, stream);
    pick_splitFC(2, 4096, zs, kPerZ);
    mfma_gemm_fc4<<<dim3(1, 2, zs), 256, 0, stream>>>(fcPh, fcPl, fw3, (float*)d_out,
                                                      100, 4096, kPerZ);
    bias_act_kernel<<<(3200 + 255) / 256, 256, 0, stream>>>((float*)d_out, fb3, 3200, 100, 0);
  }
}